// Round 9
// baseline (187.772 us; speedup 1.0000x reference)
//
#include <hip/hip_runtime.h>
#include <math.h>

#define SB 8
#define SS 2048
#define SH 768
#define ALPHA 0.5f

typedef __fp16 f16x8 __attribute__((ext_vector_type(8)));
typedef float f32x4 __attribute__((ext_vector_type(4)));

__device__ __forceinline__ float dot4(float4 a, float4 b) {
  return a.x*b.x + a.y*b.y + a.z*b.z + a.w*b.w;
}
__device__ __forceinline__ unsigned int pk2(float a, float b) {
  return __builtin_bit_cast(unsigned int, __builtin_amdgcn_cvt_pkrtz(a, b));
}
__device__ __forceinline__ void gl_lds16(const void* g, void* l) {
  __builtin_amdgcn_global_load_lds(
      (__attribute__((address_space(1))) void*)g,
      (__attribute__((address_space(3))) void*)l, 16, 0, 0);
}
#define MFMA(a, b, c) __builtin_amdgcn_mfma_f32_16x16x32_f16(a, b, c, 0, 0, 0)
#define WAITV(n) asm volatile("s_waitcnt vmcnt(" #n ")" ::: "memory")
#define WAITL() asm volatile("s_waitcnt lgkmcnt(0)" ::: "memory")
#define SB0() __builtin_amdgcn_sched_barrier(0)
#define BARR() do { SB0(); __builtin_amdgcn_s_barrier(); SB0(); } while (0)

// ws layout: Khs [SB*SS*SH] f16 (k_hat * km baked)  ~24 MB
//            | ksum [SB*SH] f32 | Nk[8] qsum[8] acc[8] cnt[8]

// K prep v9: grid (128, SB), 16 rows/block, 4 waves x 4 rows.
// All 12 row-loads per lane issued upfront (named regs) -> 12-deep MLP
// instead of the serial 8-iteration row loop.
__global__ __launch_bounds__(256) void kprep_kernel(
    const float* __restrict__ K, const float* __restrict__ km,
    const float* __restrict__ qm,
    __fp16* __restrict__ Khs, float* __restrict__ ksum,
    float* __restrict__ Nk, float* __restrict__ qsum) {
  __shared__ float4 red[4][3][64];     // 12 KB
  int b = blockIdx.y, t = threadIdx.x;
  int w = t >> 6, lane = t & 63;
  int j0 = blockIdx.x * 16;
  int jr = j0 + w * 4;
  const float4* rp0 = (const float4*)(K + ((size_t)b * SS + jr + 0) * SH);
  const float4* rp1 = (const float4*)(K + ((size_t)b * SS + jr + 1) * SH);
  const float4* rp2 = (const float4*)(K + ((size_t)b * SS + jr + 2) * SH);
  const float4* rp3 = (const float4*)(K + ((size_t)b * SS + jr + 3) * SH);
  float4 A0 = rp0[lane], A1 = rp0[lane + 64], A2 = rp0[lane + 128];
  float4 B0 = rp1[lane], B1 = rp1[lane + 64], B2 = rp1[lane + 128];
  float4 C0 = rp2[lane], C1 = rp2[lane + 64], C2 = rp2[lane + 128];
  float4 D0 = rp3[lane], D1 = rp3[lane + 64], D2 = rp3[lane + 128];
  float s0 = dot4(A0,A0) + dot4(A1,A1) + dot4(A2,A2);
  float s1 = dot4(B0,B0) + dot4(B1,B1) + dot4(B2,B2);
  float s2 = dot4(C0,C0) + dot4(C1,C1) + dot4(C2,C2);
  float s3 = dot4(D0,D0) + dot4(D1,D1) + dot4(D2,D2);
  #pragma unroll
  for (int m = 1; m < 64; m <<= 1) {
    s0 += __shfl_xor(s0, m, 64); s1 += __shfl_xor(s1, m, 64);
    s2 += __shfl_xor(s2, m, 64); s3 += __shfl_xor(s3, m, 64);
  }
  float kw0 = km[b * SS + jr + 0] / fmaxf(sqrtf(s0), 1e-12f);
  float kw1 = km[b * SS + jr + 1] / fmaxf(sqrtf(s1), 1e-12f);
  float kw2 = km[b * SS + jr + 2] / fmaxf(sqrtf(s2), 1e-12f);
  float kw3 = km[b * SS + jr + 3] / fmaxf(sqrtf(s3), 1e-12f);
  #define KST(rp, V0, V1, V2, KW, ROW) do { \
    uint2* kr_ = (uint2*)(Khs + ((size_t)b * SS + jr + (ROW)) * SH); \
    kr_[lane]       = make_uint2(pk2(V0.x*KW, V0.y*KW), pk2(V0.z*KW, V0.w*KW)); \
    kr_[lane + 64]  = make_uint2(pk2(V1.x*KW, V1.y*KW), pk2(V1.z*KW, V1.w*KW)); \
    kr_[lane + 128] = make_uint2(pk2(V2.x*KW, V2.y*KW), pk2(V2.z*KW, V2.w*KW)); \
  } while (0)
  KST(rp0, A0, A1, A2, kw0, 0); KST(rp1, B0, B1, B2, kw1, 1);
  KST(rp2, C0, C1, C2, kw2, 2); KST(rp3, D0, D1, D2, kw3, 3);
  float4 acc0, acc1, acc2;
  acc0.x = A0.x*kw0 + B0.x*kw1 + C0.x*kw2 + D0.x*kw3;
  acc0.y = A0.y*kw0 + B0.y*kw1 + C0.y*kw2 + D0.y*kw3;
  acc0.z = A0.z*kw0 + B0.z*kw1 + C0.z*kw2 + D0.z*kw3;
  acc0.w = A0.w*kw0 + B0.w*kw1 + C0.w*kw2 + D0.w*kw3;
  acc1.x = A1.x*kw0 + B1.x*kw1 + C1.x*kw2 + D1.x*kw3;
  acc1.y = A1.y*kw0 + B1.y*kw1 + C1.y*kw2 + D1.y*kw3;
  acc1.z = A1.z*kw0 + B1.z*kw1 + C1.z*kw2 + D1.z*kw3;
  acc1.w = A1.w*kw0 + B1.w*kw1 + C1.w*kw2 + D1.w*kw3;
  acc2.x = A2.x*kw0 + B2.x*kw1 + C2.x*kw2 + D2.x*kw3;
  acc2.y = A2.y*kw0 + B2.y*kw1 + C2.y*kw2 + D2.y*kw3;
  acc2.z = A2.z*kw0 + B2.z*kw1 + C2.z*kw2 + D2.z*kw3;
  acc2.w = A2.w*kw0 + B2.w*kw1 + C2.w*kw2 + D2.w*kw3;
  red[w][0][lane] = acc0; red[w][1][lane] = acc1; red[w][2][lane] = acc2;
  __syncthreads();
  if (t < 192) {
    int s = t >> 6, l = t & 63;
    float4 r0 = red[0][s][l], r1 = red[1][s][l], r2 = red[2][s][l], r3 = red[3][s][l];
    float* kp = ksum + b * SH + (s * 64 + l) * 4;
    atomicAdd(kp + 0, r0.x+r1.x+r2.x+r3.x);
    atomicAdd(kp + 1, r0.y+r1.y+r2.y+r3.y);
    atomicAdd(kp + 2, r0.z+r1.z+r2.z+r3.z);
    atomicAdd(kp + 3, r0.w+r1.w+r2.w+r3.w);
  }
  if (t < 16) {
    float pkm = km[b * SS + j0 + t];
    float pqm = qm[b * SS + j0 + t];
    #pragma unroll
    for (int m = 1; m < 16; m <<= 1) {
      pkm += __shfl_xor(pkm, m, 64);
      pqm += __shfl_xor(pqm, m, 64);
    }
    if (t == 0) { atomicAdd(&Nk[b], pkm); atomicAdd(&qsum[b], pqm); }
  }
}

// Band kernel v9: 1024 blocks x 256 thr, 16 q-rows/block, 4 waves K-split
// 4x192. Khs band staged via global_load_lds (NO dest registers -> in-flight
// depth not limited by the 44-VGPR allocation that serialized r3-r8's loads):
// 5 chunks of 16 rows (24 KB), 48 KB LDS double-buffer, counted vmcnt(6),
// raw s_barrier (no __syncthreads -> no vmcnt(0) drain), both-sides XOR
// swizzle (linear LDS dest + inverse-swizzled global source, rule #21).
__global__ __launch_bounds__(256)
__attribute__((amdgpu_waves_per_eu(2)))
void band_kernel(
    const float* __restrict__ Q, const __fp16* __restrict__ Khs,
    const float* __restrict__ temp, const float* __restrict__ qm,
    const float* __restrict__ ksum, const float* __restrict__ Nkp,
    const float* __restrict__ qsum,
    float* __restrict__ acc, int* __restrict__ cnt, float* __restrict__ out) {
  __shared__ __fp16 kst[2 * 12288];    // 48 KB: 2 x (16 rows x 768 f16)
  __shared__ f32x4 sP[4][5][64];       // 20 KB
  __shared__ float sSS[4][16], sDD[4][16];
  __shared__ float tab_s[64];
  int tid = threadIdx.x;
  int w = tid >> 6, lane = tid & 63;
  int l15 = lane & 15, quad = lane >> 4;
  int blk = blockIdx.x;
  int work = (blk & 7) * 128 + (blk >> 3);   // batch b -> XCD b
  int b = work >> 7;
  int i0 = (work & 127) * 16;

  if (tid < 64) {
    float invt = 1.0f / temp[0];
    tab_s[tid] = __expf(-ALPHA * fabsf((float)(tid - 31))) * invt;
  }
  float nk = Nkp[b];
  float qm0 = qm[b * SS + i0 + quad * 4 + 0];
  float qm1 = qm[b * SS + i0 + quad * 4 + 1];
  float qm2 = qm[b * SS + i0 + quad * 4 + 2];
  float qm3 = qm[b * SS + i0 + quad * 4 + 3];

  // staging geometry: pass u covers LDS bytes [4096u + tid*16, +16).
  // linear LDS byte d holds global byte  r*1536 + (c ^ ((r&7)<<4)).
  int r0_, r1_, r2_, r3_, r4_, r5_;
  int c0_, c1_, c2_, c3_, c4_, c5_;
  {
    #define PREP(u, RR, CC) do { \
      int d_ = (u) * 4096 + tid * 16; \
      RR = d_ / 1536; \
      int cc_ = d_ - RR * 1536; \
      CC = cc_ ^ ((RR & 7) << 4); } while (0)
    PREP(0, r0_, c0_); PREP(1, r1_, c1_); PREP(2, r2_, c2_);
    PREP(3, r3_, c3_); PREP(4, r4_, c4_); PREP(5, r5_, c5_);
  }
  const char* KbB = (const char*)(Khs + (size_t)b * SS * SH);
  char* ldsb = (char*)kst;
  #define ISSUE_STAGE(c) do { \
    int jlo_ = i0 - 32 + 16 * (c); \
    char* bb_ = ldsb + ((c) & 1) * 24576 + (w << 10); \
    gl_lds16(KbB + (size_t)min(max(jlo_ + r0_, 0), SS - 1) * 1536 + c0_, bb_ + 0 * 4096); \
    gl_lds16(KbB + (size_t)min(max(jlo_ + r1_, 0), SS - 1) * 1536 + c1_, bb_ + 1 * 4096); \
    gl_lds16(KbB + (size_t)min(max(jlo_ + r2_, 0), SS - 1) * 1536 + c2_, bb_ + 2 * 4096); \
    gl_lds16(KbB + (size_t)min(max(jlo_ + r3_, 0), SS - 1) * 1536 + c3_, bb_ + 3 * 4096); \
    gl_lds16(KbB + (size_t)min(max(jlo_ + r4_, 0), SS - 1) * 1536 + c4_, bb_ + 4 * 4096); \
    gl_lds16(KbB + (size_t)min(max(jlo_ + r5_, 0), SS - 1) * 1536 + c5_, bb_ + 5 * 4096); \
  } while (0)

  // ---- prologue: 12 Q + 12 ksum loads (this wave's 192-col K-window)
  const float* qp = Q + ((size_t)b * SS + i0 + l15) * SH + w * 192 + quad * 8;
  const float* kp = ksum + (size_t)b * SH + w * 192 + quad * 8;
  f16x8 a0_, a1_, a2_, a3_, a4_, a5_;
  float ss = 0.f, dd = 0.f;
  #define PSLICE(s, A) do { \
    float4 xa = *(const float4*)(qp + 32 * (s)); \
    float4 xb = *(const float4*)(qp + 32 * (s) + 4); \
    float4 ga = *(const float4*)(kp + 32 * (s)); \
    float4 gb = *(const float4*)(kp + 32 * (s) + 4); \
    ss += dot4(xa, xa) + dot4(xb, xb); \
    dd += dot4(xa, ga) + dot4(xb, gb); \
    uint4 u_ = make_uint4(pk2(xa.x, xa.y), pk2(xa.z, xa.w), \
                          pk2(xb.x, xb.y), pk2(xb.z, xb.w)); \
    A = __builtin_bit_cast(f16x8, u_); } while (0)
  PSLICE(0, a0_); PSLICE(1, a1_); PSLICE(2, a2_);
  PSLICE(3, a3_); PSLICE(4, a4_); PSLICE(5, a5_);

  // DMA for chunks 0,1 (issued after prologue loads: stage waits stay counted)
  ISSUE_STAGE(0); ISSUE_STAGE(1);

  ss += __shfl_xor(ss, 16, 64); ss += __shfl_xor(ss, 32, 64);
  dd += __shfl_xor(dd, 16, 64); dd += __shfl_xor(dd, 32, 64);
  if (quad == 0) { sSS[w][l15] = ss; sDD[w][l15] = dd; }

  // ds_read physical offsets (constant across chunks)
  int o0_, o1_, o2_, o3_, o4_, o5_;
  {
    #define RPREP(s, OO) OO = l15 * 1536 + (((w * 384) + (s) * 64 + quad * 16) ^ ((l15 & 7) << 4))
    RPREP(0, o0_); RPREP(1, o1_); RPREP(2, o2_);
    RPREP(3, o3_); RPREP(4, o4_); RPREP(5, o5_);
  }
  #define DOCHUNK(c) do { \
    const char* tb_ = ldsb + ((c) & 1) * 24576; \
    f16x8 b0_ = *(const f16x8*)(tb_ + o0_); \
    f16x8 b1_ = *(const f16x8*)(tb_ + o1_); \
    f16x8 b2_ = *(const f16x8*)(tb_ + o2_); \
    f16x8 b3_ = *(const f16x8*)(tb_ + o3_); \
    f16x8 b4_ = *(const f16x8*)(tb_ + o4_); \
    f16x8 b5_ = *(const f16x8*)(tb_ + o5_); \
    f32x4 d_ = {0, 0, 0, 0}; \
    d_ = MFMA(a0_, b0_, d_); d_ = MFMA(a1_, b1_, d_); \
    d_ = MFMA(a2_, b2_, d_); d_ = MFMA(a3_, b3_, d_); \
    d_ = MFMA(a4_, b4_, d_); d_ = MFMA(a5_, b5_, d_); \
    sP[w][c][lane] = d_; } while (0)

  // ---- 5 chunks, 2-deep DMA pipeline, raw barriers, counted vmcnt
  WAITV(6); BARR(); DOCHUNK(0); BARR(); ISSUE_STAGE(2);
  WAITV(6); BARR(); DOCHUNK(1); BARR(); ISSUE_STAGE(3);
  WAITV(6); BARR(); DOCHUNK(2); BARR(); ISSUE_STAGE(4);
  WAITV(6); BARR(); DOCHUNK(3); BARR();
  WAITV(0); BARR(); DOCHUNK(4);
  WAITL(); BARR();                     // sP / sSS / tab_s visible to all

  // ---- epilogue (all waves redundantly; tid 0 publishes)
  float qws[4], d0s[4];
  float qmr[4] = {qm0, qm1, qm2, qm3};
  #pragma unroll
  for (int reg = 0; reg < 4; ++reg) {
    int r = quad * 4 + reg;
    float ssr = sSS[0][r] + sSS[1][r] + sSS[2][r] + sSS[3][r];
    float ddr = sDD[0][r] + sDD[1][r] + sDD[2][r] + sDD[3][r];
    qws[reg] = qmr[reg] / fmaxf(sqrtf(ssr), 1e-12f);
    d0s[reg] = ddr;
  }
  float an[4] = {0,0,0,0}, ad[4] = {0,0,0,0};
  #pragma unroll
  for (int t = 0; t < 5; ++t) {
    f32x4 v = sP[0][t][lane] + sP[1][t][lane]
            + sP[2][t][lane] + sP[3][t][lane];
    int j = i0 - 32 + 16 * t + l15;
    float vmask = ((unsigned)j < SS) ? 1.0f : 0.0f;
    int idxb = 16 * t + l15 - 1;        // = (j - i0) + 31
    #pragma unroll
    for (int reg = 0; reg < 4; ++reg) {
      float sv = v[reg] * qws[reg];     // kw baked into Khs
      int idx = min(max(idxb - quad * 4 - reg, 0), 63);
      float ev = (__expf(sv * tab_s[idx]) - 1.0f) * vmask;
      an[reg] += ev * sv;
      ad[reg] += ev;
    }
  }
  float tot = 0.f;
  #pragma unroll
  for (int reg = 0; reg < 4; ++reg) {
    float a = an[reg], e = ad[reg];
    a += __shfl_xor(a, 1, 64); a += __shfl_xor(a, 2, 64);
    a += __shfl_xor(a, 4, 64); a += __shfl_xor(a, 8, 64);
    e += __shfl_xor(e, 1, 64); e += __shfl_xor(e, 2, 64);
    e += __shfl_xor(e, 4, 64); e += __shfl_xor(e, 8, 64);
    tot += (qws[reg] * d0s[reg] + a) / (nk + e);
  }
  tot += __shfl_xor(tot, 16, 64);
  tot += __shfl_xor(tot, 32, 64);
  if (tid == 0) {
    atomicAdd(&acc[b], tot);
    __threadfence();
    if (atomicAdd(&cnt[b], 1) == 127) { // last of 128 blocks for batch b
      float a2 = atomicAdd(&acc[b], 0.0f);
      out[b] = a2 / fmaxf(qsum[b], 1.0f);
    }
  }
}

extern "C" void kernel_launch(void* const* d_in, const int* in_sizes, int n_in,
                              void* d_out, int out_size, void* d_ws, size_t ws_size,
                              hipStream_t stream) {
  const float* Q    = (const float*)d_in[0];
  const float* K    = (const float*)d_in[1];
  const float* qm   = (const float*)d_in[2];
  const float* km   = (const float*)d_in[3];
  const float* temp = (const float*)d_in[4];
  float* outp = (float*)d_out;

  const size_t KHS_BYTES = (size_t)SB * SS * SH * 2;  // ~24 MB (fits ws, proven)
  __fp16* Khs = (__fp16*)d_ws;
  float* ksum = (float*)((char*)d_ws + KHS_BYTES);
  float* Nk   = ksum + SB * SH;
  float* qsum = Nk + 8;
  float* accb = qsum + 8;
  int*   cnt  = (int*)(accb + 8);

  (void)hipMemsetAsync(ksum, 0, (SB * SH + 32) * sizeof(float), stream);

  kprep_kernel<<<dim3(128, SB), 256, 0, stream>>>(K, km, qm, Khs, ksum, Nk, qsum);
  band_kernel<<<1024, 256, 0, stream>>>(Q, Khs, temp, qm, ksum, Nk,
                                        qsum, accb, cnt, outp);
}